// Round 7
// baseline (432.655 us; speedup 1.0000x reference)
//
#include <hip/hip_runtime.h>
#include <hip/hip_bf16.h>
#include <stdint.h>

typedef __hip_bfloat16 bf16;
typedef float f32x4 __attribute__((ext_vector_type(4)));
typedef float f32x16 __attribute__((ext_vector_type(16)));
typedef short v8s __attribute__((ext_vector_type(8)));
typedef __bf16 v8bf __attribute__((ext_vector_type(8)));
typedef unsigned int v4u __attribute__((ext_vector_type(4)));
typedef unsigned int u32;

static constexpr int MROWS = 8192;   // B*N
static constexpr int DM    = 1024;   // d_model
static constexpr int DFF   = 4096;
static constexpr int SEQ   = 2048;

__device__ __forceinline__ f32x4 mfma16(v8s a, v8s b, f32x4 c) {
  return __builtin_amdgcn_mfma_f32_16x16x32_bf16(
      __builtin_bit_cast(v8bf, a), __builtin_bit_cast(v8bf, b), c, 0, 0, 0);
}
__device__ __forceinline__ f32x16 mfma32(v8s a, v8s b, f32x16 c) {
  return __builtin_amdgcn_mfma_f32_32x32x16_bf16(
      __builtin_bit_cast(v8bf, a), __builtin_bit_cast(v8bf, b), c, 0, 0, 0);
}

__device__ __forceinline__ void gload_lds16(const void* g, void* l) {
  __builtin_amdgcn_global_load_lds(
      (const __attribute__((address_space(1))) void*)g,
      (__attribute__((address_space(3))) void*)l, 16, 0, 0);
}

__device__ __forceinline__ u32 cvtpk_bf16(float a, float b) {
  u32 r;
  asm("v_cvt_pk_bf16_f32 %0, %1, %2" : "=v"(r) : "v"(a), "v"(b));
  return r;
}
// x' = {x.lo32, y.lo32}; y' = {x.hi32, y.hi32}
__device__ __forceinline__ void pl32swap(u32& x, u32& y) {
  asm volatile("v_permlane32_swap_b32 %0, %1" : "+v"(x), "+v"(y));
}
// native 2^x (libm exp2f lowers to slow OCML polynomial)
__device__ __forceinline__ float fast_exp2(float x) {
  float r;
  asm("v_exp_f32 %0, %1" : "=v"(r) : "v"(x));
  return r;
}

// ---------------- weight transpose + cast: W[K][N] f32 -> WT[N][K] bf16 ----
__global__ __launch_bounds__(256) void transpose_cast(
    const float* __restrict__ W, bf16* __restrict__ WT, int K, int N) {
  __shared__ float tile[32][33];
  const int c0 = blockIdx.x * 32;
  const int r0 = blockIdx.y * 32;
  const int tx = threadIdx.x & 31, ty = threadIdx.x >> 5;
  #pragma unroll
  for (int i = 0; i < 32; i += 8)
    tile[ty + i][tx] = W[(size_t)(r0 + ty + i) * N + c0 + tx];
  __syncthreads();
  #pragma unroll
  for (int i = 0; i < 32; i += 8)
    WT[(size_t)(c0 + ty + i) * K + r0 + tx] = __float2bfloat16(tile[tx][ty + i]);
}

// ---------------- mean-only layernorm ----------------
__global__ __launch_bounds__(256) void ln_novar_kernel(
    const float* __restrict__ x, const float* __restrict__ w,
    const float* __restrict__ b, bf16* __restrict__ ob, float* __restrict__ of) {
  const int row = blockIdx.x;
  const int t = threadIdx.x;
  const float4 v = ((const float4*)(x + (size_t)row * DM))[t];
  float s = v.x + v.y + v.z + v.w;
  #pragma unroll
  for (int off = 32; off > 0; off >>= 1) s += __shfl_down(s, off, 64);
  __shared__ float wsum[4];
  if ((t & 63) == 0) wsum[t >> 6] = s;
  __syncthreads();
  const float u = (wsum[0] + wsum[1] + wsum[2] + wsum[3]) * (1.0f / DM);
  const float4 wv = ((const float4*)w)[t];
  const float4 bv = ((const float4*)b)[t];
  const float o0 = wv.x * (v.x - u) + bv.x;
  const float o1 = wv.y * (v.y - u) + bv.y;
  const float o2 = wv.z * (v.z - u) + bv.z;
  const float o3 = wv.w * (v.w - u) + bv.w;
  bf16* op = ob + (size_t)row * DM + t * 4;
  op[0] = __float2bfloat16(o0); op[1] = __float2bfloat16(o1);
  op[2] = __float2bfloat16(o2); op[3] = __float2bfloat16(o3);
  if (of) {
    float4 o4; o4.x = o0; o4.y = o1; o4.z = o2; o4.w = o3;
    ((float4*)(of + (size_t)row * DM))[t] = o4;
  }
}

// ---------------- GEMM: C[M][N] = A[M][K](bf16) * BT[N][K](bf16)^T --------
// Phase-split pipelined schedule (T3+T4+T5): BM=128 BN=256 BK=64, 512 thr
// (8 waves 2Mx4N, 64x64 each). 3-buffer LDS; per K-tile 2 phases (kk0/kk1);
// each phase: 8 ds_read_b128 || stage 1 half-tile of t+2 (3 gload_lds) ->
// [ph2: vmcnt(6), never 0 in steady state] -> barrier -> 16 MFMA -> barrier.
// Loads issued 3-4 phases before their wait. XCD chunk + GROUP_M raster.
#define BM 128
#define BN 256
#define BK 64
#define ASZ (BM * BK)              // 8192 elems
#define BSZ (BN * BK)              // 16384 elems
template <int EPI>
__global__ __launch_bounds__(512) void gemm_bt(
    const bf16* __restrict__ A, const bf16* __restrict__ BT,
    bf16* __restrict__ Cb, float* __restrict__ Cf,
    const float* __restrict__ bias, const float* __restrict__ res,
    int M, int Nn, int K) {
  __shared__ __align__(16) bf16 S[3][ASZ + BSZ];   // 3 x 48 KB = 144 KB

  const int tid = threadIdx.x;
  const int lane = tid & 63;
  const int wave = tid >> 6;
  const int wr = wave >> 2;        // 0..1  (M)
  const int wcn = wave & 3;        // 0..3  (N)

  // ----- block swizzle: XCD chunking (nwg%8==0 for all our grids) + raster
  const int nwg = gridDim.x;
  const int nbx = Nn / BN;
  int bid = (blockIdx.x & 7) * (nwg >> 3) + (blockIdx.x >> 3);
  const int GM = 4;
  const int grp = bid / (GM * nbx);
  const int rem = bid - grp * (GM * nbx);
  const int by = grp * GM + (rem & (GM - 1));
  const int bx = rem >> 2;                     // GM==4
  const int tM = by * BM, tN = bx * BN;

  f32x4 acc[4][4] = {};
  const int nk = K / BK;

  // stage half 'hf' of K-tile kt into buffer buf: 3 gload_lds per thread.
  // hf0: A rows 0-63  + B rows 0-127 ; hf1: A rows 64-127 + B rows 128-255.
  // XOR-swizzled source k, linear LDS dest.
  auto STAGE_H = [&](int buf, int kt, int hf) {
    const int k0 = kt * BK;
    bf16* Ab = &S[buf][0];
    bf16* Bb = &S[buf][ASZ];
    {
      const int slot = hf * 512 + tid;           // A: 512 slots per half
      const int row = slot >> 3, s = slot & 7;
      const int kk = ((s ^ (row & 7)) << 3);
      gload_lds16(A + (size_t)(tM + row) * K + k0 + kk, (void*)(Ab + slot * 8));
    }
    #pragma unroll
    for (int c2 = 0; c2 < 2; ++c2) {
      const int slot = hf * 1024 + c2 * 512 + tid;  // B: 1024 slots per half
      const int row = slot >> 3, s = slot & 7;
      const int kk = ((s ^ (row & 7)) << 3);
      gload_lds16(BT + (size_t)(tN + row) * K + k0 + kk, (void*)(Bb + slot * 8));
    }
  };

  // prologue: stage tiles 0 and 1 (12 loads), wait tile 0 (leave tile 1's 6)
  STAGE_H(0, 0, 0); STAGE_H(0, 0, 1);
  STAGE_H(1, 1, 0); STAGE_H(1, 1, 1);
  asm volatile("s_waitcnt vmcnt(6)" ::: "memory");
  __builtin_amdgcn_s_barrier();
  asm volatile("" ::: "memory");

  for (int kt = 0; kt < nk; ++kt) {
    const int cur = kt % 3;
    const bf16* Ab = &S[cur][0];
    const bf16* Bb = &S[cur][ASZ];
    #pragma unroll
    for (int kk = 0; kk < 2; ++kk) {
      const int kslot = kk * 4 + (lane >> 4);
      v8s af[4], bfr[4];
      #pragma unroll
      for (int m = 0; m < 4; ++m) {
        const int row = wr * 64 + m * 16 + (lane & 15);
        af[m] = *(const v8s*)(Ab + (row * 8 + (kslot ^ (row & 7))) * 8);
      }
      #pragma unroll
      for (int n = 0; n < 4; ++n) {
        const int row = wcn * 64 + n * 16 + (lane & 15);
        bfr[n] = *(const v8s*)(Bb + (row * 8 + (kslot ^ (row & 7))) * 8);
      }
      // stage one half-tile of kt+2 into the free buffer
      if (kt + 2 < nk) STAGE_H((kt + 2) % 3, kt + 2, kk);
      // counted wait once per K-tile (ph2): tile kt+1 ready, kt+2's 6 in flight
      if (kk == 1) {
        if (kt + 2 < nk) asm volatile("s_waitcnt vmcnt(6)" ::: "memory");
        else             asm volatile("s_waitcnt vmcnt(0)" ::: "memory");
      }
      __builtin_amdgcn_s_barrier();
      asm volatile("" ::: "memory");
      __builtin_amdgcn_s_setprio(1);
      #pragma unroll
      for (int m = 0; m < 4; ++m)
        #pragma unroll
        for (int n = 0; n < 4; ++n)
          acc[m][n] = mfma16(af[m], bfr[n], acc[m][n]);
      __builtin_amdgcn_s_setprio(0);
      asm volatile("" ::: "memory");
      __builtin_amdgcn_s_barrier();
      asm volatile("" ::: "memory");
    }
  }

  #pragma unroll
  for (int m = 0; m < 4; ++m) {
    #pragma unroll
    for (int n = 0; n < 4; ++n) {
      const int row0 = tM + wr * 64 + m * 16 + ((lane >> 4) << 2);
      const int col = tN + wcn * 64 + n * 16 + (lane & 15);
      #pragma unroll
      for (int r = 0; r < 4; ++r) {
        const size_t idx = (size_t)(row0 + r) * Nn + col;
        float v = acc[m][n][r];
        if (EPI == 0) {
          Cb[idx] = __float2bfloat16(v);
        } else if (EPI == 1) {
          v += bias[col];
          v = fmaxf(v, 0.0f);
          Cb[idx] = __float2bfloat16(v);
        } else {
          v += bias[col] + res[idx];
          Cf[idx] = v;
        }
      }
    }
  }
}

// ---------------- repack K/V into per-tile chunk-major form ----------------
// krep[bh][kt][dc][key][8] = K[b, kt*64+key, h, dc*8+e]
// vrep[bh][kt][kc][d  ][8] = V[b, kt*64+kc*8+e, h, d]
__global__ __launch_bounds__(256) void repack_kv(
    const bf16* __restrict__ qkv, bf16* __restrict__ krep,
    bf16* __restrict__ vrep) {
  const int bhkt = blockIdx.x;  // bh*32 + kt
  const int bh = bhkt >> 5, kt = bhkt & 31;
  const int b = bh >> 4, h = bh & 15;
  const size_t obase = (size_t)bhkt * 4096;
  #pragma unroll
  for (int it = 0; it < 16; ++it) {
    const int o = it * 256 + threadIdx.x;  // 0..4095
    const int ch = o >> 9, rowi = (o >> 3) & 63, e = o & 7;
    krep[obase + o] =
        qkv[(size_t)(b * SEQ + kt * 64 + rowi) * 3072 + 1024 + h * 64 + ch * 8 + e];
    vrep[obase + o] =
        qkv[(size_t)(b * SEQ + kt * 64 + ch * 8 + e) * 3072 + 2048 + h * 64 + rowi];
  }
}

// ---------------- flash attention: 4 waves x 32 q-rows, swapped QK^T ------
// grid 1024 = 16 qt x 64 bh -> 4 blocks/CU (4 independent barrier groups).
#define PPV(i) ((i) < 16 ? s0[(i) & 15] : s1[(i) & 15])
__global__ __launch_bounds__(256, 4) void attn_kernel(
    const bf16* __restrict__ qkv, const bf16* __restrict__ krep,
    const bf16* __restrict__ vrep, bf16* __restrict__ ob) {
  const int qt = blockIdx.x & 15;
  const int bh = blockIdx.x >> 4;   // same-bh blocks adjacent -> L2 reuse
  const int b = bh >> 4, h = bh & 15;
  const int tid = threadIdx.x;
  const int lane = tid & 63, wave = tid >> 6;
  const int c = lane & 31, hi = lane >> 5;
  const float CEXP = 0.180336880111120426f;  // 0.125 * log2(e)

  __shared__ __align__(16) bf16 Ks[2][4096];
  __shared__ __align__(16) bf16 Vs[2][4096];

  // Q fragments (B-operand): q-col = c, k-elem = ks*16 + hi*8 + j
  const int qrow = qt * 128 + wave * 32 + c;
  const bf16* qp = qkv + (size_t)(b * SEQ + qrow) * 3072 + h * 64;
  v8s qf[4];
  #pragma unroll
  for (int ks = 0; ks < 4; ++ks)
    qf[ks] = *(const v8s*)(qp + ks * 16 + hi * 8);

  f32x16 o0 = {}, o1 = {};
  float mrow = -1e30f, lrow = 0.0f;

  const size_t tilebase = (size_t)(bh * 32) * 4096;
  #pragma unroll
  for (int j = 0; j < 2; ++j) {
    gload_lds16(krep + tilebase + (tid + j * 256) * 8, &Ks[0][(tid + j * 256) * 8]);
    gload_lds16(vrep + tilebase + (tid + j * 256) * 8, &Vs[0][(tid + j * 256) * 8]);
  }
  asm volatile("s_waitcnt vmcnt(0)" ::: "memory");
  __builtin_amdgcn_s_barrier();
  asm volatile("" ::: "memory");

  for (int kt = 0; kt < 32; ++kt) {
    const int cur = kt & 1;
    if (kt < 31) {
      const size_t nb = tilebase + (size_t)(kt + 1) * 4096;
      #pragma unroll
      for (int j = 0; j < 2; ++j) {
        gload_lds16(krep + nb + (tid + j * 256) * 8, &Ks[cur ^ 1][(tid + j * 256) * 8]);
        gload_lds16(vrep + nb + (tid + j * 256) * 8, &Vs[cur ^ 1][(tid + j * 256) * 8]);
      }
    }
    const bf16* KB = Ks[cur];
    const bf16* VB = Vs[cur];

    // S^T = K Q : rows = keys, cols = q.  Lane holds 32 keys of row q=c.
    f32x16 s0 = {}, s1 = {};
    __builtin_amdgcn_s_setprio(1);
    #pragma unroll
    for (int ks = 0; ks < 4; ++ks) {
      const int ch = (2 * ks + hi) * 512;
      v8s a0 = *(const v8s*)(KB + ch + c * 8);
      v8s a1 = *(const v8s*)(KB + ch + (c + 32) * 8);
      s0 = mfma32(a0, qf[ks], s0);
      s1 = mfma32(a1, qf[ks], s1);
    }
    __builtin_amdgcn_s_setprio(0);

    // online softmax, fully in-register (raw-logit units; scale folded)
    float mA = -1e30f, mB = -1e30f;   // v_max3 trees
    #pragma unroll
    for (int i = 0; i < 16; i += 2) {
      mA = fmaxf(fmaxf(s0[i], s0[i + 1]), mA);
      mB = fmaxf(fmaxf(s1[i], s1[i + 1]), mB);
    }
    float tmax = fmaxf(mA, mB);
    tmax = fmaxf(tmax, __shfl_xor(tmax, 32, 64));
    if (__any(tmax - mrow > 64.0f)) {   // defer-max: e^8 headroom
      const float mnew = fmaxf(mrow, tmax);
      const float ef = fast_exp2((mrow - mnew) * CEXP);
      mrow = mnew;
      lrow *= ef;
      #pragma unroll
      for (int r = 0; r < 16; ++r) {
        const float efq = __shfl(ef, (r & 3) + 8 * (r >> 2) + 4 * hi, 64);
        o0[r] *= efq;
        o1[r] *= efq;
      }
    }
    const float nmc = -mrow * CEXP;
    float rs0 = 0.0f, rs1 = 0.0f;
    #pragma unroll
    for (int i = 0; i < 16; ++i) {
      s0[i] = fast_exp2(fmaf(s0[i], CEXP, nmc));
      s1[i] = fast_exp2(fmaf(s1[i], CEXP, nmc));
      rs0 += s0[i];
      rs1 += s1[i];
    }
    float rs = rs0 + rs1;
    rs += __shfl_xor(rs, 32, 64);
    lrow += rs;

    // P -> A-operand fragments via cvt_pk + permlane32_swap (T12)
    v8s pa[4];
    #pragma unroll
    for (int ks = 0; ks < 4; ++ks) {
      u32 x  = cvtpk_bf16(PPV(8 * ks + 0), PPV(8 * ks + 1));
      u32 y  = cvtpk_bf16(PPV(8 * ks + 4), PPV(8 * ks + 5));
      u32 x2 = cvtpk_bf16(PPV(8 * ks + 2), PPV(8 * ks + 3));
      u32 y2 = cvtpk_bf16(PPV(8 * ks + 6), PPV(8 * ks + 7));
      pl32swap(x, y);
      pl32swap(x2, y2);
      v4u w; w.x = x; w.y = x2; w.z = y; w.w = y2;
      pa[ks] = __builtin_bit_cast(v8s, w);
    }

    // O += P V
    __builtin_amdgcn_s_setprio(1);
    #pragma unroll
    for (int ks = 0; ks < 4; ++ks) {
      const int ch = (2 * ks + hi) * 512;
      v8s b0 = *(const v8s*)(VB + ch + c * 8);
      v8s b1 = *(const v8s*)(VB + ch + (c + 32) * 8);
      o0 = mfma32(pa[ks], b0, o0);
      o1 = mfma32(pa[ks], b1, o1);
    }
    __builtin_amdgcn_s_setprio(0);

    asm volatile("s_waitcnt vmcnt(0)" ::: "memory");
    __builtin_amdgcn_s_barrier();
    asm volatile("" ::: "memory");
  }

  // epilogue: rows q = (r&3)+8*(r>>2)+4*hi, col d = dblk*32 + c
  const float rl = 1.0f / lrow;
  const size_t orow0 = (size_t)(b * SEQ + qt * 128 + wave * 32);
  #pragma unroll
  for (int r = 0; r < 16; ++r) {
    const int q = (r & 3) + 8 * (r >> 2) + 4 * hi;
    const float rq = __shfl(rl, q, 64);
    bf16* op = ob + (orow0 + q) * DM + h * 64;
    op[c] = __float2bfloat16(o0[r] * rq);
    op[32 + c] = __float2bfloat16(o1[r] * rq);
  }
}

// ---------------- launch ---------------------------------------------------
extern "C" void kernel_launch(void* const* d_in, const int* in_sizes, int n_in,
                              void* d_out, int out_size, void* d_ws,
                              size_t ws_size, hipStream_t stream) {
  const float* src   = (const float*)d_in[0];
  const float* pnw   = (const float*)d_in[1];
  const float* pnb   = (const float*)d_in[2];
  const float* wq    = (const float*)d_in[3];
  const float* wk    = (const float*)d_in[4];
  const float* wv    = (const float*)d_in[5];
  const float* wproj = (const float*)d_in[6];
  const float* bproj = (const float*)d_in[7];
  const float* n1w   = (const float*)d_in[8];
  const float* n1b   = (const float*)d_in[9];
  const float* w1    = (const float*)d_in[10];
  const float* b1    = (const float*)d_in[11];
  const float* w2    = (const float*)d_in[12];
  const float* b2    = (const float*)d_in[13];
  float* out = (float*)d_out;

  char* ws = (char*)d_ws;
  size_t off = 0;
  bf16* WTqkv = (bf16*)(ws + off); off += (size_t)3072 * 1024 * 2;
  bf16* WTprj = (bf16*)(ws + off); off += (size_t)1024 * 1024 * 2;
  bf16* WT1   = (bf16*)(ws + off); off += (size_t)4096 * 1024 * 2;
  bf16* WT2   = (bf16*)(ws + off); off += (size_t)1024 * 4096 * 2;
  bf16* xb    = (bf16*)(ws + off); off += (size_t)MROWS * DM * 2;
  bf16* qkvb  = (bf16*)(ws + off); off += (size_t)MROWS * 3072 * 2;
  bf16* obuf  = (bf16*)(ws + off); off += (size_t)MROWS * DM * 2;
  float* yf   = (float*)(ws + off); off += (size_t)MROWS * DM * 4;
  bf16* h1    = (bf16*)(ws + off); off += (size_t)MROWS * DFF * 2;
  // krep/vrep alias h1 (h1 written only in step 8, after attention)
  bf16* krep = h1;
  bf16* vrep = h1 + (size_t)64 * SEQ * 64;

  const dim3 blk(256);
  const dim3 gblk(512);

  transpose_cast<<<dim3(32, 32), blk, 0, stream>>>(wq, WTqkv, 1024, 1024);
  transpose_cast<<<dim3(32, 32), blk, 0, stream>>>(wk, WTqkv + 1024 * 1024, 1024, 1024);
  transpose_cast<<<dim3(32, 32), blk, 0, stream>>>(wv, WTqkv + 2048 * 1024, 1024, 1024);
  transpose_cast<<<dim3(32, 32), blk, 0, stream>>>(wproj, WTprj, 1024, 1024);
  transpose_cast<<<dim3(128, 32), blk, 0, stream>>>(w1, WT1, 1024, 4096);
  transpose_cast<<<dim3(32, 128), blk, 0, stream>>>(w2, WT2, 4096, 1024);

  ln_novar_kernel<<<MROWS, blk, 0, stream>>>(src, pnw, pnb, xb, nullptr);

  gemm_bt<0><<<dim3((3072 / BN) * (MROWS / BM)), gblk, 0, stream>>>(
      xb, WTqkv, qkvb, nullptr, nullptr, nullptr, MROWS, 3072, 1024);

  repack_kv<<<dim3(64 * 32), blk, 0, stream>>>(qkvb, krep, vrep);

  attn_kernel<<<dim3(16 * 64), dim3(256), 0, stream>>>(qkvb, krep, vrep, obuf);

  gemm_bt<2><<<dim3((1024 / BN) * (MROWS / BM)), gblk, 0, stream>>>(
      obuf, WTprj, nullptr, yf, bproj, src, MROWS, 1024, 1024);

  ln_novar_kernel<<<MROWS, blk, 0, stream>>>(yf, n1w, n1b, xb, out);

  gemm_bt<1><<<dim3((4096 / BN) * (MROWS / BM)), gblk, 0, stream>>>(
      xb, WT1, h1, nullptr, b1, nullptr, MROWS, 4096, 1024);

  gemm_bt<2><<<dim3((1024 / BN) * (MROWS / BM)), gblk, 0, stream>>>(
      h1, WT2, nullptr, out, b2, out, MROWS, 1024, 4096);
}

// Round 8
// 417.578 us; speedup vs baseline: 1.0361x; 1.0361x over previous
//
#include <hip/hip_runtime.h>
#include <hip/hip_bf16.h>
#include <stdint.h>

typedef __hip_bfloat16 bf16;
typedef float f32x4 __attribute__((ext_vector_type(4)));
typedef float f32x16 __attribute__((ext_vector_type(16)));
typedef short v8s __attribute__((ext_vector_type(8)));
typedef __bf16 v8bf __attribute__((ext_vector_type(8)));
typedef unsigned int v4u __attribute__((ext_vector_type(4)));
typedef unsigned int u32;

static constexpr int MROWS = 8192;   // B*N
static constexpr int DM    = 1024;   // d_model
static constexpr int DFF   = 4096;
static constexpr int SEQ   = 2048;

__device__ __forceinline__ f32x4 mfma16(v8s a, v8s b, f32x4 c) {
  return __builtin_amdgcn_mfma_f32_16x16x32_bf16(
      __builtin_bit_cast(v8bf, a), __builtin_bit_cast(v8bf, b), c, 0, 0, 0);
}
__device__ __forceinline__ f32x16 mfma32(v8s a, v8s b, f32x16 c) {
  return __builtin_amdgcn_mfma_f32_32x32x16_bf16(
      __builtin_bit_cast(v8bf, a), __builtin_bit_cast(v8bf, b), c, 0, 0, 0);
}

__device__ __forceinline__ void gload_lds16(const void* g, void* l) {
  __builtin_amdgcn_global_load_lds(
      (const __attribute__((address_space(1))) void*)g,
      (__attribute__((address_space(3))) void*)l, 16, 0, 0);
}

__device__ __forceinline__ u32 cvtpk_bf16(float a, float b) {
  u32 r;
  asm("v_cvt_pk_bf16_f32 %0, %1, %2" : "=v"(r) : "v"(a), "v"(b));
  return r;
}
// x' = {x.lo32, y.lo32}; y' = {x.hi32, y.hi32}
__device__ __forceinline__ void pl32swap(u32& x, u32& y) {
  asm volatile("v_permlane32_swap_b32 %0, %1" : "+v"(x), "+v"(y));
}
// native 2^x (libm exp2f lowers to slow OCML polynomial)
__device__ __forceinline__ float fast_exp2(float x) {
  float r;
  asm("v_exp_f32 %0, %1" : "=v"(r) : "v"(x));
  return r;
}

// ---------------- weight transpose + cast: W[K][N] f32 -> WT[N][K] bf16 ----
__global__ __launch_bounds__(256) void transpose_cast(
    const float* __restrict__ W, bf16* __restrict__ WT, int K, int N) {
  __shared__ float tile[32][33];
  const int c0 = blockIdx.x * 32;
  const int r0 = blockIdx.y * 32;
  const int tx = threadIdx.x & 31, ty = threadIdx.x >> 5;
  #pragma unroll
  for (int i = 0; i < 32; i += 8)
    tile[ty + i][tx] = W[(size_t)(r0 + ty + i) * N + c0 + tx];
  __syncthreads();
  #pragma unroll
  for (int i = 0; i < 32; i += 8)
    WT[(size_t)(c0 + ty + i) * K + r0 + tx] = __float2bfloat16(tile[tx][ty + i]);
}

// ---------------- mean-only layernorm ----------------
__global__ __launch_bounds__(256) void ln_novar_kernel(
    const float* __restrict__ x, const float* __restrict__ w,
    const float* __restrict__ b, bf16* __restrict__ ob, float* __restrict__ of) {
  const int row = blockIdx.x;
  const int t = threadIdx.x;
  const float4 v = ((const float4*)(x + (size_t)row * DM))[t];
  float s = v.x + v.y + v.z + v.w;
  #pragma unroll
  for (int off = 32; off > 0; off >>= 1) s += __shfl_down(s, off, 64);
  __shared__ float wsum[4];
  if ((t & 63) == 0) wsum[t >> 6] = s;
  __syncthreads();
  const float u = (wsum[0] + wsum[1] + wsum[2] + wsum[3]) * (1.0f / DM);
  const float4 wv = ((const float4*)w)[t];
  const float4 bv = ((const float4*)b)[t];
  const float o0 = wv.x * (v.x - u) + bv.x;
  const float o1 = wv.y * (v.y - u) + bv.y;
  const float o2 = wv.z * (v.z - u) + bv.z;
  const float o3 = wv.w * (v.w - u) + bv.w;
  bf16* op = ob + (size_t)row * DM + t * 4;
  op[0] = __float2bfloat16(o0); op[1] = __float2bfloat16(o1);
  op[2] = __float2bfloat16(o2); op[3] = __float2bfloat16(o3);
  if (of) {
    float4 o4; o4.x = o0; o4.y = o1; o4.z = o2; o4.w = o3;
    ((float4*)(of + (size_t)row * DM))[t] = o4;
  }
}

// ---------------- GEMM: C[M][N] = A[M][K](bf16) * BT[N][K](bf16)^T --------
// Register-double-buffered fragment pipeline: each ds_read burst overlaps an
// independent MFMA burst (the real T3 mechanism). 3-buffer LDS, 2-ahead
// staging, counted vmcnt(6) (never 0 in steady state), 2 barriers/K-tile.
// EPI 0: C->bf16   1: relu(C+bias)->bf16   2: C+bias+res->f32
// EPI 3: QKV fused repack (Q->Cb row-major; K->krep, V->vrep scatter)
#define BM 128
#define BN 256
#define BK 64
#define ASZ (BM * BK)              // 8192 elems
#define BSZ (BN * BK)              // 16384 elems
template <int EPI>
__global__ __launch_bounds__(512, 2) void gemm_bt(
    const bf16* __restrict__ A, const bf16* __restrict__ BT,
    bf16* __restrict__ Cb, float* __restrict__ Cf,
    const float* __restrict__ bias, const float* __restrict__ res,
    int M, int Nn, int K) {
  __shared__ __align__(16) bf16 S[3][ASZ + BSZ];   // 3 x 48 KB = 144 KB

  const int tid = threadIdx.x;
  const int lane = tid & 63;
  const int wave = tid >> 6;
  const int wr = wave >> 2;        // 0..1  (M)
  const int wcn = wave & 3;        // 0..3  (N)

  // ----- block swizzle: XCD chunking (nwg%8==0 for all our grids) + raster
  const int nwg = gridDim.x;
  const int nbx = Nn / BN;
  int bid = (blockIdx.x & 7) * (nwg >> 3) + (blockIdx.x >> 3);
  const int GM = 4;
  const int grp = bid / (GM * nbx);
  const int rem = bid - grp * (GM * nbx);
  const int by = grp * GM + (rem & (GM - 1));
  const int bx = rem >> 2;                     // GM==4
  const int tM = by * BM, tN = bx * BN;

  f32x4 acc[4][4] = {};
  const int nk = K / BK;

  // stage K-tile kt into buffer buf: 6 gload_lds/thread (2 A + 4 B halves)
  auto STAGE = [&](int buf, int kt) {
    const int k0 = kt * BK;
    bf16* Ab = &S[buf][0];
    bf16* Bb = &S[buf][ASZ];
    #pragma unroll
    for (int c = 0; c < 2; ++c) {
      const int slot = c * 512 + tid;
      const int row = slot >> 3, s = slot & 7;
      const int kk = ((s ^ (row & 7)) << 3);
      gload_lds16(A + (size_t)(tM + row) * K + k0 + kk, (void*)(Ab + slot * 8));
    }
    #pragma unroll
    for (int c = 0; c < 4; ++c) {
      const int slot = c * 512 + tid;
      const int row = slot >> 3, s = slot & 7;
      const int kk = ((s ^ (row & 7)) << 3);
      gload_lds16(BT + (size_t)(tN + row) * K + k0 + kk, (void*)(Bb + slot * 8));
    }
  };

  // fragment load for phase kk (0/1) of buffer buf
  auto LD = [&](v8s* af, v8s* bfr, int buf, int kk) {
    const bf16* Ab = &S[buf][0];
    const bf16* Bb = &S[buf][ASZ];
    const int kslot = kk * 4 + (lane >> 4);
    #pragma unroll
    for (int m = 0; m < 4; ++m) {
      const int row = wr * 64 + m * 16 + (lane & 15);
      af[m] = *(const v8s*)(Ab + (row * 8 + (kslot ^ (row & 7))) * 8);
    }
    #pragma unroll
    for (int n = 0; n < 4; ++n) {
      const int row = wcn * 64 + n * 16 + (lane & 15);
      bfr[n] = *(const v8s*)(Bb + (row * 8 + (kslot ^ (row & 7))) * 8);
    }
  };

  v8s fA0[4], fB0[4], fA1[4], fB1[4];

  // prologue: stage tiles 0,1; wait tile 0 (tile 1's 6 stay in flight)
  STAGE(0, 0);
  STAGE(1, 1);
  asm volatile("s_waitcnt vmcnt(6)" ::: "memory");
  __builtin_amdgcn_s_barrier();
  asm volatile("" ::: "memory");
  LD(fA0, fB0, 0, 0);

  for (int kt = 0; kt < nk; ++kt) {
    const int cur = kt % 3;
    if (kt + 2 < nk) STAGE((kt + 2) % 3, kt + 2);

    LD(fA1, fB1, cur, 1);              // ds_read ph1 of tile kt ...
    __builtin_amdgcn_s_setprio(1);     // ... overlaps MFMA ph0 of tile kt
    #pragma unroll
    for (int m = 0; m < 4; ++m)
      #pragma unroll
      for (int n = 0; n < 4; ++n)
        acc[m][n] = mfma16(fA0[m], fB0[n], acc[m][n]);
    __builtin_amdgcn_s_setprio(0);

    if (kt + 2 < nk) asm volatile("s_waitcnt vmcnt(6)" ::: "memory");
    else             asm volatile("s_waitcnt vmcnt(0)" ::: "memory");
    __builtin_amdgcn_s_barrier();      // buf[kt+1] visible to all waves
    asm volatile("" ::: "memory");

    if (kt + 1 < nk) LD(fA0, fB0, (kt + 1) % 3, 0);  // ds_read ph0 tile kt+1
    __builtin_amdgcn_s_setprio(1);     // ... overlaps MFMA ph1 of tile kt
    #pragma unroll
    for (int m = 0; m < 4; ++m)
      #pragma unroll
      for (int n = 0; n < 4; ++n)
        acc[m][n] = mfma16(fA1[m], fB1[n], acc[m][n]);
    __builtin_amdgcn_s_setprio(0);

    asm volatile("" ::: "memory");
    __builtin_amdgcn_s_barrier();      // buf[kt] consumed before STAGE(kt+3)
    asm volatile("" ::: "memory");
  }

  #pragma unroll
  for (int m = 0; m < 4; ++m) {
    #pragma unroll
    for (int n = 0; n < 4; ++n) {
      const int row0 = tM + wr * 64 + m * 16 + ((lane >> 4) << 2);
      const int col = tN + wcn * 64 + n * 16 + (lane & 15);
      #pragma unroll
      for (int r = 0; r < 4; ++r) {
        const int row = row0 + r;
        float v = acc[m][n][r];
        if (EPI == 0) {
          Cb[(size_t)row * Nn + col] = __float2bfloat16(v);
        } else if (EPI == 1) {
          v += bias[col];
          v = fmaxf(v, 0.0f);
          Cb[(size_t)row * Nn + col] = __float2bfloat16(v);
        } else if (EPI == 2) {
          v += bias[col] + res[(size_t)row * Nn + col];
          Cf[(size_t)row * Nn + col] = v;
        } else {
          // EPI 3: QKV fused repack. sec: 0=Q (row-major), 1=K, 2=V.
          const int sec = tN >> 10;
          if (sec == 0) {
            Cb[(size_t)row * Nn + col] = __float2bfloat16(v);
          } else {
            const int b = row >> 11, nn2 = row & 2047;
            const int ktt = nn2 >> 6, key = nn2 & 63;
            if (sec == 1) {
              const int ck = col - 1024;
              const int h = ck >> 6, dc = (ck >> 3) & 7, e = ck & 7;
              bf16* krp = (bf16*)(void*)bias;
              krp[((size_t)((b * 16 + h) * 32 + ktt)) * 4096 + dc * 512 +
                  key * 8 + e] = __float2bfloat16(v);
            } else {
              const int cv = col - 2048;
              const int h = cv >> 6, d = cv & 63;
              const int kc = key >> 3, e2 = key & 7;
              bf16* vrp = (bf16*)(void*)res;
              vrp[((size_t)((b * 16 + h) * 32 + ktt)) * 4096 + kc * 512 +
                  d * 8 + e2] = __float2bfloat16(v);
            }
          }
        }
      }
    }
  }
}

// ---------------- flash attention: 4 waves x 32 q-rows, swapped QK^T ------
// grid 1024 = 16 qt x 64 bh -> 4 blocks/CU (4 independent barrier groups).
#define PPV(i) ((i) < 16 ? s0[(i) & 15] : s1[(i) & 15])
__global__ __launch_bounds__(256, 4) void attn_kernel(
    const bf16* __restrict__ qkv, const bf16* __restrict__ krep,
    const bf16* __restrict__ vrep, bf16* __restrict__ ob) {
  const int qt = blockIdx.x & 15;
  const int bh = blockIdx.x >> 4;   // same-bh blocks adjacent -> L2 reuse
  const int b = bh >> 4, h = bh & 15;
  const int tid = threadIdx.x;
  const int lane = tid & 63, wave = tid >> 6;
  const int c = lane & 31, hi = lane >> 5;
  const float CEXP = 0.180336880111120426f;  // 0.125 * log2(e)

  __shared__ __align__(16) bf16 Ks[2][4096];
  __shared__ __align__(16) bf16 Vs[2][4096];

  // Q fragments (B-operand): q-col = c, k-elem = ks*16 + hi*8 + j
  const int qrow = qt * 128 + wave * 32 + c;
  const bf16* qp = qkv + (size_t)(b * SEQ + qrow) * 3072 + h * 64;
  v8s qf[4];
  #pragma unroll
  for (int ks = 0; ks < 4; ++ks)
    qf[ks] = *(const v8s*)(qp + ks * 16 + hi * 8);

  f32x16 o0 = {}, o1 = {};
  float mrow = -1e30f, lrow = 0.0f;

  const size_t tilebase = (size_t)(bh * 32) * 4096;
  #pragma unroll
  for (int j = 0; j < 2; ++j) {
    gload_lds16(krep + tilebase + (tid + j * 256) * 8, &Ks[0][(tid + j * 256) * 8]);
    gload_lds16(vrep + tilebase + (tid + j * 256) * 8, &Vs[0][(tid + j * 256) * 8]);
  }
  asm volatile("s_waitcnt vmcnt(0)" ::: "memory");
  __builtin_amdgcn_s_barrier();
  asm volatile("" ::: "memory");

  for (int kt = 0; kt < 32; ++kt) {
    const int cur = kt & 1;
    if (kt < 31) {
      const size_t nb = tilebase + (size_t)(kt + 1) * 4096;
      #pragma unroll
      for (int j = 0; j < 2; ++j) {
        gload_lds16(krep + nb + (tid + j * 256) * 8, &Ks[cur ^ 1][(tid + j * 256) * 8]);
        gload_lds16(vrep + nb + (tid + j * 256) * 8, &Vs[cur ^ 1][(tid + j * 256) * 8]);
      }
    }
    const bf16* KB = Ks[cur];
    const bf16* VB = Vs[cur];

    // S^T = K Q : rows = keys, cols = q.  Lane holds 32 keys of row q=c.
    f32x16 s0 = {}, s1 = {};
    __builtin_amdgcn_s_setprio(1);
    #pragma unroll
    for (int ks = 0; ks < 4; ++ks) {
      const int ch = (2 * ks + hi) * 512;
      v8s a0 = *(const v8s*)(KB + ch + c * 8);
      v8s a1 = *(const v8s*)(KB + ch + (c + 32) * 8);
      s0 = mfma32(a0, qf[ks], s0);
      s1 = mfma32(a1, qf[ks], s1);
    }
    __builtin_amdgcn_s_setprio(0);

    // online softmax, fully in-register (raw-logit units; scale folded)
    float mA = -1e30f, mB = -1e30f;   // v_max3 trees
    #pragma unroll
    for (int i = 0; i < 16; i += 2) {
      mA = fmaxf(fmaxf(s0[i], s0[i + 1]), mA);
      mB = fmaxf(fmaxf(s1[i], s1[i + 1]), mB);
    }
    float tmax = fmaxf(mA, mB);
    tmax = fmaxf(tmax, __shfl_xor(tmax, 32, 64));
    if (__any(tmax - mrow > 64.0f)) {   // defer-max: e^8 headroom
      const float mnew = fmaxf(mrow, tmax);
      const float ef = fast_exp2((mrow - mnew) * CEXP);
      mrow = mnew;
      lrow *= ef;
      #pragma unroll
      for (int r = 0; r < 16; ++r) {
        const float efq = __shfl(ef, (r & 3) + 8 * (r >> 2) + 4 * hi, 64);
        o0[r] *= efq;
        o1[r] *= efq;
      }
    }
    const float nmc = -mrow * CEXP;
    float rs0 = 0.0f, rs1 = 0.0f;
    #pragma unroll
    for (int i = 0; i < 16; ++i) {
      s0[i] = fast_exp2(fmaf(s0[i], CEXP, nmc));
      s1[i] = fast_exp2(fmaf(s1[i], CEXP, nmc));
      rs0 += s0[i];
      rs1 += s1[i];
    }
    float rs = rs0 + rs1;
    rs += __shfl_xor(rs, 32, 64);
    lrow += rs;

    // P -> A-operand fragments via cvt_pk + permlane32_swap (T12)
    v8s pa[4];
    #pragma unroll
    for (int ks = 0; ks < 4; ++ks) {
      u32 x  = cvtpk_bf16(PPV(8 * ks + 0), PPV(8 * ks + 1));
      u32 y  = cvtpk_bf16(PPV(8 * ks + 4), PPV(8 * ks + 5));
      u32 x2 = cvtpk_bf16(PPV(8 * ks + 2), PPV(8 * ks + 3));
      u32 y2 = cvtpk_bf16(PPV(8 * ks + 6), PPV(8 * ks + 7));
      pl32swap(x, y);
      pl32swap(x2, y2);
      v4u w; w.x = x; w.y = x2; w.z = y; w.w = y2;
      pa[ks] = __builtin_bit_cast(v8s, w);
    }

    // O += P V
    __builtin_amdgcn_s_setprio(1);
    #pragma unroll
    for (int ks = 0; ks < 4; ++ks) {
      const int ch = (2 * ks + hi) * 512;
      v8s b0 = *(const v8s*)(VB + ch + c * 8);
      v8s b1 = *(const v8s*)(VB + ch + (c + 32) * 8);
      o0 = mfma32(pa[ks], b0, o0);
      o1 = mfma32(pa[ks], b1, o1);
    }
    __builtin_amdgcn_s_setprio(0);

    asm volatile("s_waitcnt vmcnt(0)" ::: "memory");
    __builtin_amdgcn_s_barrier();
    asm volatile("" ::: "memory");
  }

  // epilogue: rows q = (r&3)+8*(r>>2)+4*hi, col d = dblk*32 + c
  const float rl = 1.0f / lrow;
  const size_t orow0 = (size_t)(b * SEQ + qt * 128 + wave * 32);
  #pragma unroll
  for (int r = 0; r < 16; ++r) {
    const int q = (r & 3) + 8 * (r >> 2) + 4 * hi;
    const float rq = __shfl(rl, q, 64);
    bf16* op = ob + (orow0 + q) * DM + h * 64;
    op[c] = __float2bfloat16(o0[r] * rq);
    op[32 + c] = __float2bfloat16(o1[r] * rq);
  }
}

// ---------------- launch ---------------------------------------------------
extern "C" void kernel_launch(void* const* d_in, const int* in_sizes, int n_in,
                              void* d_out, int out_size, void* d_ws,
                              size_t ws_size, hipStream_t stream) {
  const float* src   = (const float*)d_in[0];
  const float* pnw   = (const float*)d_in[1];
  const float* pnb   = (const float*)d_in[2];
  const float* wq    = (const float*)d_in[3];
  const float* wk    = (const float*)d_in[4];
  const float* wv    = (const float*)d_in[5];
  const float* wproj = (const float*)d_in[6];
  const float* bproj = (const float*)d_in[7];
  const float* n1w   = (const float*)d_in[8];
  const float* n1b   = (const float*)d_in[9];
  const float* w1    = (const float*)d_in[10];
  const float* b1    = (const float*)d_in[11];
  const float* w2    = (const float*)d_in[12];
  const float* b2    = (const float*)d_in[13];
  float* out = (float*)d_out;

  char* ws = (char*)d_ws;
  size_t off = 0;
  bf16* WTqkv = (bf16*)(ws + off); off += (size_t)3072 * 1024 * 2;
  bf16* WTprj = (bf16*)(ws + off); off += (size_t)1024 * 1024 * 2;
  bf16* WT1   = (bf16*)(ws + off); off += (size_t)4096 * 1024 * 2;
  bf16* WT2   = (bf16*)(ws + off); off += (size_t)1024 * 4096 * 2;
  bf16* xb    = (bf16*)(ws + off); off += (size_t)MROWS * DM * 2;
  bf16* qkvb  = (bf16*)(ws + off); off += (size_t)MROWS * 3072 * 2;
  bf16* obuf  = (bf16*)(ws + off); off += (size_t)MROWS * DM * 2;
  float* yf   = (float*)(ws + off); off += (size_t)MROWS * DM * 4;
  bf16* h1    = (bf16*)(ws + off); off += (size_t)MROWS * DFF * 2;
  // krep/vrep alias h1 (h1 written only in step 8, after attention)
  bf16* krep = h1;
  bf16* vrep = h1 + (size_t)64 * SEQ * 64;

  const dim3 blk(256);
  const dim3 gblk(512);

  transpose_cast<<<dim3(32, 32), blk, 0, stream>>>(wq, WTqkv, 1024, 1024);
  transpose_cast<<<dim3(32, 32), blk, 0, stream>>>(wk, WTqkv + 1024 * 1024, 1024, 1024);
  transpose_cast<<<dim3(32, 32), blk, 0, stream>>>(wv, WTqkv + 2048 * 1024, 1024, 1024);
  transpose_cast<<<dim3(32, 32), blk, 0, stream>>>(wproj, WTprj, 1024, 1024);
  transpose_cast<<<dim3(128, 32), blk, 0, stream>>>(w1, WT1, 1024, 4096);
  transpose_cast<<<dim3(32, 128), blk, 0, stream>>>(w2, WT2, 4096, 1024);

  ln_novar_kernel<<<MROWS, blk, 0, stream>>>(src, pnw, pnb, xb, nullptr);

  // QKV gemm with fused K/V repack (EPI 3): krep/vrep passed via bias/res
  gemm_bt<3><<<dim3((3072 / BN) * (MROWS / BM)), gblk, 0, stream>>>(
      xb, WTqkv, qkvb, nullptr, (const float*)krep, (const float*)vrep,
      MROWS, 3072, 1024);

  attn_kernel<<<dim3(16 * 64), dim3(256), 0, stream>>>(qkvb, krep, vrep, obuf);

  gemm_bt<2><<<dim3((1024 / BN) * (MROWS / BM)), gblk, 0, stream>>>(
      obuf, WTprj, nullptr, yf, bproj, src, MROWS, 1024, 1024);

  ln_novar_kernel<<<MROWS, blk, 0, stream>>>(yf, n1w, n1b, xb, out);

  gemm_bt<1><<<dim3((4096 / BN) * (MROWS / BM)), gblk, 0, stream>>>(
      xb, WT1, h1, nullptr, b1, nullptr, MROWS, 4096, 1024);

  gemm_bt<2><<<dim3((1024 / BN) * (MROWS / BM)), gblk, 0, stream>>>(
      h1, WT2, nullptr, out, b2, out, MROWS, 1024, 4096);
}